// Round 7
// baseline (383.392 us; speedup 1.0000x reference)
//
#include <hip/hip_runtime.h>
#include <hip/hip_bf16.h>

#define NNODES 100000
#define NEDGES 1600000
#define NC 25               // coarse buckets of 4096 nodes (dst>>12)
#define CAP1 68000          // coarse slack (mean 65536, +~10 sigma)
#define NBUCK 391           // fine buckets of 256 nodes
#define BCAP 4800           // fine slack (mean 4096, +11 sigma)
#define SPLIT_TILE 2048
#define NSPLIT ((NEDGES + SPLIT_TILE - 1) / SPLIT_TILE)  // 782
#define T2TILES 17          // ceil(CAP1 / 4096)
#define NTILES (NNODES / 16) // 6250 dense tiles, exact

typedef short short8 __attribute__((ext_vector_type(8)));
typedef unsigned short ushx8 __attribute__((ext_vector_type(8)));
typedef float floatx4 __attribute__((ext_vector_type(4)));

// f32 -> bf16 RNE
__device__ __forceinline__ unsigned short f2b(float f) {
    unsigned u = __float_as_uint(f);
    u += 0x7fffu + ((u >> 16) & 1u);
    return (unsigned short)(u >> 16);
}

__device__ __forceinline__ void acc8(float* a, ushx8 u) {
#pragma unroll
    for (int i = 0; i < 8; ++i)
        a[i] += __uint_as_float((unsigned)u[i] << 16);
}

// ---------------- split pass 1: 25 coarse buckets by dst>>12 ----------------
// packed u32 = (src << 12) | (dst & 4095)   (src < 2^17)
__global__ __launch_bounds__(256) void split1_kernel(
    const int* __restrict__ dst, const int* __restrict__ src,
    int* __restrict__ gcur1, unsigned* __restrict__ cpairs) {
    __shared__ int lhist[NC];
    __shared__ int lstart[NC];
    __shared__ int ldst[SPLIT_TILE];
    int t = threadIdx.x;
    if (t < NC) lhist[t] = 0;
    __syncthreads();
    int base = blockIdx.x * SPLIT_TILE;
    int n = min(SPLIT_TILE, NEDGES - base);
    for (int i = t; i < n; i += 256) {
        int d = dst[base + i];
        ldst[i] = d;
        atomicAdd(&lhist[d >> 12], 1);
    }
    __syncthreads();
    if (t < NC) {
        int c = lhist[t];
        lstart[t] = (c > 0) ? atomicAdd(&gcur1[t], c) : 0;
        lhist[t] = 0;  // reuse as local cursor
    }
    __syncthreads();
    for (int i = t; i < n; i += 256) {
        int d = ldst[i];
        int k = d >> 12;
        int s = src[base + i];
        int pos = lstart[k] + atomicAdd(&lhist[k], 1);
        cpairs[(size_t)k * CAP1 + pos] = ((unsigned)s << 12) | (unsigned)(d & 4095);
    }
}

// ---------------- split pass 2: coarse -> 16 fine buckets, ballot-ranked ----------------
// repack to (src << 8) | (dst & 255)
__global__ __launch_bounds__(256) void split2_kernel(
    const unsigned* __restrict__ cpairs, const int* __restrict__ gcur1,
    int* __restrict__ gcur2, unsigned* __restrict__ fpairs) {
    int c = blockIdx.x / T2TILES;
    int tile = blockIdx.x % T2TILES;
    int cnt = gcur1[c];
    int base = tile * 4096;
    if (base >= cnt) return;
    int n = min(4096, cnt - base);
    __shared__ unsigned stash[4096];
    __shared__ int lhist[16];
    __shared__ int lstart[16];
    __shared__ int chunkbase[64][16];
    int t = threadIdx.x;
    int lane = t & 63;
    int w = t >> 6;
    if (t < 16) lhist[t] = 0;
    __syncthreads();
    const unsigned* pb = cpairs + (size_t)c * CAP1 + base;
    int nchunk = (n + 63) >> 6;
    // pass 1: chunked ballot counting (no contended atomics)
    for (int ch = w; ch < nchunk; ch += 4) {
        int i = ch * 64 + lane;
        unsigned p = 0;
        int f = -1;
        if (i < n) {
            p = pb[i];
            stash[i] = p;
            f = (int)((p >> 8) & 15u);
        }
#pragma unroll
        for (int b = 0; b < 16; ++b) {
            unsigned long long m = __ballot(f == b);
            if (lane == b) {
                int cb = __popcll(m);
                chunkbase[ch][b] = (cb > 0) ? atomicAdd(&lhist[b], cb) : 0;
            }
        }
    }
    __syncthreads();
    if (t < 16) {
        int cc = lhist[t];
        lstart[t] = (cc > 0) ? atomicAdd(&gcur2[c * 16 + t], cc) : 0;
    }
    __syncthreads();
    // pass 2: ballot-ranked scatter
    for (int ch = w; ch < nchunk; ch += 4) {
        int i = ch * 64 + lane;
        unsigned p = 0;
        int f = -1;
        if (i < n) {
            p = stash[i];
            f = (int)((p >> 8) & 15u);
        }
        unsigned long long lt = (1ull << lane) - 1ull;
        int myrank = 0;
#pragma unroll
        for (int b = 0; b < 16; ++b) {
            unsigned long long m = __ballot(f == b);
            if (f == b) myrank = __popcll(m & lt);
        }
        if (i < n) {
            int pos = lstart[f] + chunkbase[ch][f] + myrank;
            fpairs[(size_t)(c * 16 + f) * BCAP + pos] = ((p >> 12) << 8) | (p & 255u);
        }
    }
}

// ---------------- exclusive scan of 391 fine-bucket counts ----------------
__global__ void bucketscan_kernel(const int* __restrict__ gcur2, int* __restrict__ basearr) {
    __shared__ int lds[512];
    int t = threadIdx.x;
    int v = (t < NBUCK) ? gcur2[t] : 0;
    lds[t] = v;
    __syncthreads();
    for (int s = 1; s < 512; s <<= 1) {
        int u = (t >= s) ? lds[t - s] : 0;
        __syncthreads();
        lds[t] += u;
        __syncthreads();
    }
    if (t < NBUCK) basearr[t] = lds[t] - v;
}

// ---------------- finalize: per-bucket CSR build + deg/rowoff/dinv + g0b ----------------
__global__ __launch_bounds__(256) void finalize_kernel(
    const unsigned* __restrict__ fpairs, const int* __restrict__ gcur2,
    const int* __restrict__ basearr, const float* __restrict__ x,
    int* __restrict__ col, int* __restrict__ deg, int* __restrict__ rowoff,
    float* __restrict__ dinv, unsigned short* __restrict__ g0b) {
    __shared__ int ldeg[256];
    __shared__ int lcur[256];
    __shared__ float ldi[256];
    __shared__ int lsc[256];
    int k = blockIdx.x;
    int t = threadIdx.x;
    int node0 = k << 8;
    int ncount = min(256, NNODES - node0);
    int base = basearr[k];
    int count = gcur2[k];
    ldeg[t] = 0;
    __syncthreads();
    const unsigned* pb = fpairs + (size_t)k * BCAP;
    for (int i = t; i < count; i += 256) {
        atomicAdd(&ldeg[pb[i] & 255], 1);
    }
    __syncthreads();
    int a = ldeg[t];
    lsc[t] = a;
    __syncthreads();
    for (int s = 1; s < 256; s <<= 1) {
        int v = (t >= s) ? lsc[t - s] : 0;
        __syncthreads();
        lsc[t] += v;
        __syncthreads();
    }
    int excl = lsc[t] - a;
    lcur[t] = base + excl;
    if (t < ncount) {
        int n0 = node0 + t;
        rowoff[n0] = base + excl;
        deg[n0] = a;
        float di = (a > 0) ? rsqrtf((float)a) : 0.0f;
        ldi[t] = di;
        dinv[n0] = di;
    }
    __syncthreads();
    for (int i = t; i < count; i += 256) {
        unsigned p = pb[i];
        int dl = (int)(p & 255u);
        int s = (int)(p >> 8);
        int pos = atomicAdd(&lcur[dl], 1);
        col[pos] = s;
    }
    // fused g0b = bf16(dinv * x)
    const float4* x4 = (const float4*)x;
    int f4count = ncount * 16;
    int b4 = node0 * 16;
    for (int j = t; j < f4count; j += 256) {
        float di = ldi[j >> 4];
        float4 v = x4[b4 + j];
        ushort4 u;
        u.x = f2b(di * v.x); u.y = f2b(di * v.y);
        u.z = f2b(di * v.z); u.w = f2b(di * v.w);
        *(ushort4*)(g0b + (size_t)(b4 + j) * 4) = u;
    }
}

// ---------------- kprop gather: one node per wave, 8 groups x 8 lanes x 16B ----------------
// MODE 0: h1b = bf16(x + dinv*sum), g1b = bf16(dinv*h1)   (residual = f32 x)
// MODE 1: h2b = bf16(h1b + dinv*sum)                       (residual = bf16)
template <int MODE>
__global__ __launch_bounds__(256) void gatherw_kernel(
    const unsigned short* __restrict__ vin, const float* __restrict__ hinf,
    const unsigned short* __restrict__ hinb,
    unsigned short* __restrict__ out0, unsigned short* __restrict__ out1,
    const int* __restrict__ rowoff, const int* __restrict__ deg,
    const int* __restrict__ col, const float* __restrict__ dinv) {
    int node = blockIdx.x * 4 + (threadIdx.x >> 6);  // 25000*4 == 100000 exactly
    int lane = threadIdx.x & 63;
    int sub = lane & 7;
    int g = lane >> 3;
    int beg = rowoff[node];
    int dg = deg[node];
    int end = beg + dg;
    float af[8] = {0.f, 0.f, 0.f, 0.f, 0.f, 0.f, 0.f, 0.f};
    float bf[8] = {0.f, 0.f, 0.f, 0.f, 0.f, 0.f, 0.f, 0.f};
    int e = beg + g;
    for (; e + 8 < end; e += 16) {
        int c0 = col[e];
        int c1 = col[e + 8];
        ushx8 u0 = *(const ushx8*)(vin + (size_t)c0 * 64 + sub * 8);
        ushx8 u1 = *(const ushx8*)(vin + (size_t)c1 * 64 + sub * 8);
        acc8(af, u0);
        acc8(bf, u1);
    }
    if (e < end) {
        int c0 = col[e];
        ushx8 u0 = *(const ushx8*)(vin + (size_t)c0 * 64 + sub * 8);
        acc8(af, u0);
    }
#pragma unroll
    for (int i = 0; i < 8; ++i) {
        float v = af[i] + bf[i];
        v += __shfl_xor(v, 8);
        v += __shfl_xor(v, 16);
        v += __shfl_xor(v, 32);
        af[i] = v;
    }
    if (lane < 8) {
        size_t off = (size_t)node * 64 + lane * 8;
        float di = dinv[node];
        float hv[8];
        if (MODE == 0) {
            float4 h0 = *(const float4*)(hinf + off);
            float4 h1 = *(const float4*)(hinf + off + 4);
            hv[0] = h0.x; hv[1] = h0.y; hv[2] = h0.z; hv[3] = h0.w;
            hv[4] = h1.x; hv[5] = h1.y; hv[6] = h1.z; hv[7] = h1.w;
        } else {
            ushx8 u = *(const ushx8*)(hinb + off);
#pragma unroll
            for (int i = 0; i < 8; ++i) hv[i] = __uint_as_float((unsigned)u[i] << 16);
        }
        ushx8 uh, ug;
#pragma unroll
        for (int i = 0; i < 8; ++i) {
            float hn = hv[i] + di * af[i];
            uh[i] = f2b(hn);
            if (MODE == 0) ug[i] = f2b(di * hn);
        }
        *(ushx8*)(out0 + off) = uh;
        if (MODE == 0) *(ushx8*)(out1 + off) = ug;
    }
}

// ---------------- fused SAGE1: mean-gather + MFMA + SELU, bf16 out ----------------
// Block = 256 thr = 4 waves; wave = one 16-node tile. Wave-private LDS agg stash.
__global__ __launch_bounds__(256) void aggdense1_kernel(
    const unsigned short* __restrict__ hb,   // h2b (gathered AND row operand)
    unsigned short* __restrict__ h3b,
    const float* __restrict__ W2l, const float* __restrict__ W2r,
    const float* __restrict__ b2,
    const int* __restrict__ rowoff, const int* __restrict__ deg,
    const int* __restrict__ col) {
    __shared__ unsigned short Wt[64 * 136];       // [j][k], k = 0..127, pad to 136
    __shared__ unsigned short aggT[4][16 * 68];   // per-wave [n][f], pad to 68
    int t = threadIdx.x;
    for (int idx = t; idx < 128 * 64; idx += 256) {
        int k = idx >> 6, j = idx & 63;
        float v = (k < 64) ? W2l[k * 64 + j] : W2r[(k - 64) * 64 + j];
        Wt[j * 136 + k] = f2b(v);
    }
    __syncthreads();
    int w = t >> 6, lane = t & 63;
    int tile = blockIdx.x * 4 + w;
    if (tile >= NTILES) return;
    int node0 = tile * 16;
    int sub = lane & 7;
    int g = lane >> 3;
    // ---- gather phase: 16 nodes, mean aggregate -> aggT[w] (bf16) ----
    for (int n = 0; n < 16; ++n) {
        int node = node0 + n;
        int beg = rowoff[node];
        int dg = deg[node];
        int end = beg + dg;
        float af[8] = {0.f, 0.f, 0.f, 0.f, 0.f, 0.f, 0.f, 0.f};
        float bf[8] = {0.f, 0.f, 0.f, 0.f, 0.f, 0.f, 0.f, 0.f};
        int e = beg + g;
        for (; e + 8 < end; e += 16) {
            int c0 = col[e];
            int c1 = col[e + 8];
            ushx8 u0 = *(const ushx8*)(hb + (size_t)c0 * 64 + sub * 8);
            ushx8 u1 = *(const ushx8*)(hb + (size_t)c1 * 64 + sub * 8);
            acc8(af, u0);
            acc8(bf, u1);
        }
        if (e < end) {
            int c0 = col[e];
            ushx8 u0 = *(const ushx8*)(hb + (size_t)c0 * 64 + sub * 8);
            acc8(af, u0);
        }
#pragma unroll
        for (int i = 0; i < 8; ++i) {
            float v = af[i] + bf[i];
            v += __shfl_xor(v, 8);
            v += __shfl_xor(v, 16);
            v += __shfl_xor(v, 32);
            af[i] = v;
        }
        if (lane < 8) {
            float r = 1.0f / (float)(dg > 0 ? dg : 1);
            ushx8 u;
#pragma unroll
            for (int i = 0; i < 8; ++i) u[i] = f2b(af[i] * r);
            *(ushx8*)&aggT[w][n * 68 + lane * 8] = u;
        }
    }
    asm volatile("s_waitcnt lgkmcnt(0)" ::: "memory");
    // ---- MFMA phase ----
    int jj = lane & 15, kg = lane >> 4;
    short8 afrag[4];
    afrag[0] = *(const short8*)&aggT[w][jj * 68 + kg * 8];
    afrag[1] = *(const short8*)&aggT[w][jj * 68 + 32 + kg * 8];
    const unsigned short* hp = hb + (size_t)(node0 + jj) * 64 + kg * 8;
    afrag[2] = *(const short8*)hp;
    afrag[3] = *(const short8*)(hp + 32);
    const float lam = 1.0507009873554804934193349852946f;
    const float alp = 1.6732632423543772848170429916717f;
#pragma unroll
    for (int nt = 0; nt < 4; ++nt) {
        short8 bfrag[4];
#pragma unroll
        for (int s = 0; s < 4; ++s)
            bfrag[s] = *(const short8*)&Wt[(nt * 16 + jj) * 136 + s * 32 + kg * 8];
        floatx4 acc = {0.f, 0.f, 0.f, 0.f};
#pragma unroll
        for (int s = 0; s < 4; ++s)
            acc = __builtin_amdgcn_mfma_f32_16x16x32_bf16(afrag[s], bfrag[s], acc, 0, 0, 0);
        float bias = b2[nt * 16 + jj];
#pragma unroll
        for (int r = 0; r < 4; ++r) {
            float v = acc[r] + bias;
            float o = (v > 0.0f) ? lam * v : lam * alp * expm1f(v);
            int node = node0 + kg * 4 + r;
            h3b[(size_t)node * 64 + nt * 16 + jj] = f2b(o);
        }
    }
}

// ---------------- fused SAGE2: mean-gather + MFMA + softmax(16) ----------------
__global__ __launch_bounds__(256) void aggdense2_kernel(
    const unsigned short* __restrict__ hb,   // h3b
    float* __restrict__ out,
    const float* __restrict__ W3l, const float* __restrict__ W3r,
    const float* __restrict__ b3,
    const int* __restrict__ rowoff, const int* __restrict__ deg,
    const int* __restrict__ col) {
    __shared__ unsigned short Wt[16 * 136];
    __shared__ unsigned short aggT[4][16 * 68];
    int t = threadIdx.x;
    for (int idx = t; idx < 128 * 16; idx += 256) {
        int k = idx >> 4, j = idx & 15;
        float v = (k < 64) ? W3l[k * 16 + j] : W3r[(k - 64) * 16 + j];
        Wt[j * 136 + k] = f2b(v);
    }
    __syncthreads();
    int w = t >> 6, lane = t & 63;
    int tile = blockIdx.x * 4 + w;
    if (tile >= NTILES) return;
    int node0 = tile * 16;
    int sub = lane & 7;
    int g = lane >> 3;
    for (int n = 0; n < 16; ++n) {
        int node = node0 + n;
        int beg = rowoff[node];
        int dg = deg[node];
        int end = beg + dg;
        float af[8] = {0.f, 0.f, 0.f, 0.f, 0.f, 0.f, 0.f, 0.f};
        float bf[8] = {0.f, 0.f, 0.f, 0.f, 0.f, 0.f, 0.f, 0.f};
        int e = beg + g;
        for (; e + 8 < end; e += 16) {
            int c0 = col[e];
            int c1 = col[e + 8];
            ushx8 u0 = *(const ushx8*)(hb + (size_t)c0 * 64 + sub * 8);
            ushx8 u1 = *(const ushx8*)(hb + (size_t)c1 * 64 + sub * 8);
            acc8(af, u0);
            acc8(bf, u1);
        }
        if (e < end) {
            int c0 = col[e];
            ushx8 u0 = *(const ushx8*)(hb + (size_t)c0 * 64 + sub * 8);
            acc8(af, u0);
        }
#pragma unroll
        for (int i = 0; i < 8; ++i) {
            float v = af[i] + bf[i];
            v += __shfl_xor(v, 8);
            v += __shfl_xor(v, 16);
            v += __shfl_xor(v, 32);
            af[i] = v;
        }
        if (lane < 8) {
            float r = 1.0f / (float)(dg > 0 ? dg : 1);
            ushx8 u;
#pragma unroll
            for (int i = 0; i < 8; ++i) u[i] = f2b(af[i] * r);
            *(ushx8*)&aggT[w][n * 68 + lane * 8] = u;
        }
    }
    asm volatile("s_waitcnt lgkmcnt(0)" ::: "memory");
    int jj = lane & 15, kg = lane >> 4;
    short8 afrag[4];
    afrag[0] = *(const short8*)&aggT[w][jj * 68 + kg * 8];
    afrag[1] = *(const short8*)&aggT[w][jj * 68 + 32 + kg * 8];
    const unsigned short* hp = hb + (size_t)(node0 + jj) * 64 + kg * 8;
    afrag[2] = *(const short8*)hp;
    afrag[3] = *(const short8*)(hp + 32);
    short8 bfrag[4];
#pragma unroll
    for (int s = 0; s < 4; ++s)
        bfrag[s] = *(const short8*)&Wt[jj * 136 + s * 32 + kg * 8];
    floatx4 acc = {0.f, 0.f, 0.f, 0.f};
#pragma unroll
    for (int s = 0; s < 4; ++s)
        acc = __builtin_amdgcn_mfma_f32_16x16x32_bf16(afrag[s], bfrag[s], acc, 0, 0, 0);
    float bias = b3[jj];
#pragma unroll
    for (int r = 0; r < 4; ++r) {
        float v = acc[r] + bias;
        float m = v;
        m = fmaxf(m, __shfl_xor(m, 1));
        m = fmaxf(m, __shfl_xor(m, 2));
        m = fmaxf(m, __shfl_xor(m, 4));
        m = fmaxf(m, __shfl_xor(m, 8));
        float ex = expf(v - m);
        float s2 = ex;
        s2 += __shfl_xor(s2, 1);
        s2 += __shfl_xor(s2, 2);
        s2 += __shfl_xor(s2, 4);
        s2 += __shfl_xor(s2, 8);
        int node = node0 + kg * 4 + r;
        out[(size_t)node * 16 + jj] = ex / s2;
    }
}

extern "C" void kernel_launch(void* const* d_in, const int* in_sizes, int n_in,
                              void* d_out, int out_size, void* d_ws, size_t ws_size,
                              hipStream_t stream) {
    const float* x   = (const float*)d_in[0];
    const int*   ei  = (const int*)d_in[1];
    const float* W2l = (const float*)d_in[2];
    const float* W2r = (const float*)d_in[3];
    const float* b2  = (const float*)d_in[4];
    const float* W3l = (const float*)d_in[5];
    const float* W3r = (const float*)d_in[6];
    const float* b3  = (const float*)d_in[7];
    float* out = (float*)d_out;

    const int* dst = ei;           // edge_index[0]
    const int* src = ei + NEDGES;  // edge_index[1]

    char* ws = (char*)d_ws;
    unsigned short* B0 = (unsigned short*)ws; ws += (size_t)NNODES * 64 * 2;  // g0b -> h2b
    unsigned short* B1 = (unsigned short*)ws; ws += (size_t)NNODES * 64 * 2;  // cpairs -> h1b
    unsigned short* B2 = (unsigned short*)ws; ws += (size_t)NNODES * 64 * 2;  // fpairs -> g1b -> h3b
    int*      col     = (int*)ws;      ws += (size_t)NEDGES * 4;
    int*      deg     = (int*)ws;      ws += (size_t)NNODES * 4;
    int*      rowoff  = (int*)ws;      ws += (size_t)NNODES * 4;
    float*    dinv    = (float*)ws;    ws += (size_t)NNODES * 4;
    int*      gcur1   = (int*)ws;      ws += NC * 4;
    int*      gcur2   = (int*)ws;      ws += NBUCK * 4;
    int*      basearr = (int*)ws;      ws += NBUCK * 4;

    // overlays (dead before their hosts are written):
    unsigned* cpairs = (unsigned*)B1;  // 25*68000*4 = 6.8 MB < 12.8 MB; dead after split2
    unsigned* fpairs = (unsigned*)B2;  // 391*4800*4 = 7.5 MB < 12.8 MB; dead after finalize
    unsigned short* h3b = B2;          // g1b dead after gatherw<1>

    hipMemsetAsync(gcur1, 0, (NC + NBUCK) * 4, stream);  // gcur1 + gcur2 adjacent

    split1_kernel<<<NSPLIT, 256, 0, stream>>>(dst, src, gcur1, cpairs);
    split2_kernel<<<NC * T2TILES, 256, 0, stream>>>(cpairs, gcur1, gcur2, fpairs);
    bucketscan_kernel<<<1, 512, 0, stream>>>(gcur2, basearr);
    finalize_kernel<<<NBUCK, 256, 0, stream>>>(fpairs, gcur2, basearr, x,
                                               col, deg, rowoff, dinv, B0);

    int nblk = NNODES / 4;                 // 25000, exact
    int nfused = (NTILES + 3) / 4;         // 1563
    // KProp step 1: h1b = bf16(x + dinv*sum(g0)), g1b = bf16(dinv*h1)
    gatherw_kernel<0><<<nblk, 256, 0, stream>>>(B0, x, nullptr, B1, B2, rowoff, deg, col, dinv);
    // KProp step 2: h2b = bf16(h1b + dinv*sum(g1))
    gatherw_kernel<1><<<nblk, 256, 0, stream>>>(B2, nullptr, B1, B0, nullptr, rowoff, deg, col, dinv);
    // SAGE1 fused: agg=mean(h2b[neigh]); h3b = bf16(selu(agg@W2l + h2@W2r + b2))
    aggdense1_kernel<<<nfused, 256, 0, stream>>>(B0, h3b, W2l, W2r, b2, rowoff, deg, col);
    // SAGE2 fused: agg=mean(h3b[neigh]); out = softmax(agg@W3l + h3@W3r + b3)
    aggdense2_kernel<<<nfused, 256, 0, stream>>>(h3b, out, W3l, W3r, b3, rowoff, deg, col);
}

// Round 8
// 324.739 us; speedup vs baseline: 1.1806x; 1.1806x over previous
//
#include <hip/hip_runtime.h>
#include <hip/hip_bf16.h>

#define NNODES 100000
#define NEDGES 1600000
#define NC 25               // coarse buckets of 4096 nodes (dst>>12)
#define CAP1 68000          // coarse slack (mean 65536, +~10 sigma)
#define NBUCK 391           // fine buckets of 256 nodes
#define BCAP 4800           // fine slack (mean 4096, +11 sigma)
#define SPLIT_TILE 4096
#define NSPLIT ((NEDGES + SPLIT_TILE - 1) / SPLIT_TILE)  // 391
#define T2TILES 17          // ceil(CAP1 / 4096)
#define NTILES (NNODES / 16) // 6250 dense tiles, exact

typedef short short8 __attribute__((ext_vector_type(8)));
typedef unsigned short ushx8 __attribute__((ext_vector_type(8)));
typedef float floatx4 __attribute__((ext_vector_type(4)));

// f32 -> bf16 RNE
__device__ __forceinline__ unsigned short f2b(float f) {
    unsigned u = __float_as_uint(f);
    u += 0x7fffu + ((u >> 16) & 1u);
    return (unsigned short)(u >> 16);
}

__device__ __forceinline__ void acc8(float* a, ushx8 u) {
#pragma unroll
    for (int i = 0; i < 8; ++i)
        a[i] += __uint_as_float((unsigned)u[i] << 16);
}

__device__ __forceinline__ void acc8s(float* a, ushx8 u, float s) {
#pragma unroll
    for (int i = 0; i < 8; ++i)
        a[i] = fmaf(s, __uint_as_float((unsigned)u[i] << 16), a[i]);
}

// ---------------- split pass 1: 25 coarse buckets by dst>>12 ----------------
// packed u32 = (src << 12) | (dst & 4095)   (src < 2^17)
__global__ __launch_bounds__(256) void split1_kernel(
    const int* __restrict__ dst, const int* __restrict__ src,
    int* __restrict__ gcur1, unsigned* __restrict__ cpairs) {
    __shared__ int lhist[NC];
    __shared__ int lstart[NC];
    __shared__ int ldst[SPLIT_TILE];
    int t = threadIdx.x;
    if (t < NC) lhist[t] = 0;
    __syncthreads();
    int base = blockIdx.x * SPLIT_TILE;
    int n = min(SPLIT_TILE, NEDGES - base);
    for (int i = t; i < n; i += 256) {
        int d = dst[base + i];
        ldst[i] = d;
        atomicAdd(&lhist[d >> 12], 1);
    }
    __syncthreads();
    if (t < NC) {
        int c = lhist[t];
        lstart[t] = (c > 0) ? atomicAdd(&gcur1[t], c) : 0;
        lhist[t] = 0;  // reuse as local cursor
    }
    __syncthreads();
    for (int i = t; i < n; i += 256) {
        int d = ldst[i];
        int k = d >> 12;
        int s = src[base + i];
        int pos = lstart[k] + atomicAdd(&lhist[k], 1);
        cpairs[(size_t)k * CAP1 + pos] = ((unsigned)s << 12) | (unsigned)(d & 4095);
    }
}

// ---------------- split pass 2: coarse -> 16 fine buckets each ----------------
// repack to (src << 8) | (dst & 255)
__global__ __launch_bounds__(256) void split2_kernel(
    const unsigned* __restrict__ cpairs, const int* __restrict__ gcur1,
    int* __restrict__ gcur2, unsigned* __restrict__ fpairs) {
    int c = blockIdx.x / T2TILES;
    int tile = blockIdx.x % T2TILES;
    int cnt = gcur1[c];
    int base = tile * 4096;
    if (base >= cnt) return;
    int n = min(4096, cnt - base);
    __shared__ unsigned stash[4096];
    __shared__ int lhist[16];
    __shared__ int lstart[16];
    int t = threadIdx.x;
    if (t < 16) lhist[t] = 0;
    __syncthreads();
    const unsigned* pb = cpairs + (size_t)c * CAP1 + base;
    for (int i = t; i < n; i += 256) {
        unsigned p = pb[i];
        stash[i] = p;
        atomicAdd(&lhist[(p >> 8) & 15], 1);
    }
    __syncthreads();
    if (t < 16) {
        int cc = lhist[t];
        lstart[t] = (cc > 0) ? atomicAdd(&gcur2[c * 16 + t], cc) : 0;
        lhist[t] = 0;
    }
    __syncthreads();
    for (int i = t; i < n; i += 256) {
        unsigned p = stash[i];
        int f = (p >> 8) & 15;
        int pos = lstart[f] + atomicAdd(&lhist[f], 1);
        fpairs[(size_t)(c * 16 + f) * BCAP + pos] = ((p >> 12) << 8) | (p & 255u);
    }
}

// ---------------- finalize: inline bucket scan + per-bucket CSR + dinv + g0b ----------------
__global__ __launch_bounds__(256) void finalize_kernel(
    const unsigned* __restrict__ fpairs, const int* __restrict__ gcur2,
    const float* __restrict__ x,
    int* __restrict__ col, int* __restrict__ deg, int* __restrict__ rowoff,
    float* __restrict__ dinv, unsigned short* __restrict__ g0b) {
    __shared__ int ldeg[256];
    __shared__ int lcur[256];
    __shared__ float ldi[256];
    __shared__ int lsc[256];
    __shared__ int bb[NBUCK + 1];
    int k = blockIdx.x;
    int t = threadIdx.x;
    // inline exclusive scan of all 391 bucket counts (redundant per block, ~1us)
    int a2 = (2 * t < NBUCK) ? gcur2[2 * t] : 0;
    int b2v = (2 * t + 1 < NBUCK) ? gcur2[2 * t + 1] : 0;
    int ts = a2 + b2v;
    lsc[t] = ts;
    __syncthreads();
    for (int s = 1; s < 256; s <<= 1) {
        int v = (t >= s) ? lsc[t - s] : 0;
        __syncthreads();
        lsc[t] += v;
        __syncthreads();
    }
    int excl2 = lsc[t] - ts;
    if (2 * t < NBUCK) bb[2 * t] = excl2;
    if (2 * t + 1 < NBUCK) bb[2 * t + 1] = excl2 + a2;
    ldeg[t] = 0;
    __syncthreads();
    int node0 = k << 8;
    int ncount = min(256, NNODES - node0);
    int base = bb[k];
    int count = gcur2[k];
    const unsigned* pb = fpairs + (size_t)k * BCAP;
    for (int i = t; i < count; i += 256) {
        atomicAdd(&ldeg[pb[i] & 255], 1);
    }
    __syncthreads();
    int a = ldeg[t];
    lsc[t] = a;
    __syncthreads();
    for (int s = 1; s < 256; s <<= 1) {
        int v = (t >= s) ? lsc[t - s] : 0;
        __syncthreads();
        lsc[t] += v;
        __syncthreads();
    }
    int excl = lsc[t] - a;
    lcur[t] = base + excl;
    if (t < ncount) {
        int n0 = node0 + t;
        rowoff[n0] = base + excl;
        deg[n0] = a;
        float di = (a > 0) ? rsqrtf((float)a) : 0.0f;
        ldi[t] = di;
        dinv[n0] = di;
    }
    __syncthreads();
    for (int i = t; i < count; i += 256) {
        unsigned p = pb[i];
        int dl = (int)(p & 255u);
        int s = (int)(p >> 8);
        int pos = atomicAdd(&lcur[dl], 1);
        col[pos] = s;
    }
    // fused g0b = bf16(dinv * x)
    const float4* x4 = (const float4*)x;
    int f4count = ncount * 16;
    int b4 = node0 * 16;
    for (int j = t; j < f4count; j += 256) {
        float di = ldi[j >> 4];
        float4 v = x4[b4 + j];
        ushort4 u;
        u.x = f2b(di * v.x); u.y = f2b(di * v.y);
        u.z = f2b(di * v.z); u.w = f2b(di * v.w);
        *(ushort4*)(g0b + (size_t)(b4 + j) * 4) = u;
    }
}

// ---------------- kprop/agg gather: one node per wave, 8 groups x 8 lanes x 16B ----------------
// MODE 0: h1b = bf16(x + dinv_i*sum(g0b))            (residual = f32 x; vin pre-scaled)
// MODE 1: h2b = bf16(h1b + dinv_i*sum(dinv_c*h1b))   (per-edge dinv; residual = bf16 h1b)
// MODE 2: aggb = bf16(sum/degm)
template <int MODE>
__global__ __launch_bounds__(256) void gatherw_kernel(
    const unsigned short* __restrict__ vin, const float* __restrict__ hinf,
    const unsigned short* __restrict__ hinb,
    unsigned short* __restrict__ out0,
    const int* __restrict__ rowoff, const int* __restrict__ deg,
    const int* __restrict__ col, const float* __restrict__ dinv) {
    int node = blockIdx.x * 4 + (threadIdx.x >> 6);  // 25000*4 == 100000 exactly
    int lane = threadIdx.x & 63;
    int sub = lane & 7;
    int g = lane >> 3;
    int beg = rowoff[node];
    int dg = deg[node];
    int end = beg + dg;
    float af[8] = {0.f, 0.f, 0.f, 0.f, 0.f, 0.f, 0.f, 0.f};
    float bf[8] = {0.f, 0.f, 0.f, 0.f, 0.f, 0.f, 0.f, 0.f};
    int e = beg + g;
    for (; e + 8 < end; e += 16) {
        int c0 = col[e];
        int c1 = col[e + 8];
        ushx8 u0 = *(const ushx8*)(vin + (size_t)c0 * 64 + sub * 8);
        ushx8 u1 = *(const ushx8*)(vin + (size_t)c1 * 64 + sub * 8);
        if (MODE == 1) {
            float d0 = dinv[c0];
            float d1 = dinv[c1];
            acc8s(af, u0, d0);
            acc8s(bf, u1, d1);
        } else {
            acc8(af, u0);
            acc8(bf, u1);
        }
    }
    if (e < end) {
        int c0 = col[e];
        ushx8 u0 = *(const ushx8*)(vin + (size_t)c0 * 64 + sub * 8);
        if (MODE == 1) {
            float d0 = dinv[c0];
            acc8s(af, u0, d0);
        } else {
            acc8(af, u0);
        }
    }
#pragma unroll
    for (int i = 0; i < 8; ++i) {
        float v = af[i] + bf[i];
        v += __shfl_xor(v, 8);
        v += __shfl_xor(v, 16);
        v += __shfl_xor(v, 32);
        af[i] = v;
    }
    if (lane < 8) {
        size_t off = (size_t)node * 64 + lane * 8;
        ushx8 uh;
        if (MODE <= 1) {
            float di = dinv[node];
            float hv[8];
            if (MODE == 0) {
                float4 h0 = *(const float4*)(hinf + off);
                float4 h1 = *(const float4*)(hinf + off + 4);
                hv[0] = h0.x; hv[1] = h0.y; hv[2] = h0.z; hv[3] = h0.w;
                hv[4] = h1.x; hv[5] = h1.y; hv[6] = h1.z; hv[7] = h1.w;
            } else {
                ushx8 u = *(const ushx8*)(hinb + off);
#pragma unroll
                for (int i = 0; i < 8; ++i) hv[i] = __uint_as_float((unsigned)u[i] << 16);
            }
#pragma unroll
            for (int i = 0; i < 8; ++i) uh[i] = f2b(hv[i] + di * af[i]);
        } else {
            float r = 1.0f / (float)(dg > 0 ? dg : 1);
#pragma unroll
            for (int i = 0; i < 8; ++i) uh[i] = f2b(af[i] * r);
        }
        *(ushx8*)(out0 + off) = uh;
    }
}

// ---------------- dense1 (MFMA): h3 = selu([agg|h2] @ [W2l;W2r] + b2), bf16 out ----------------
__global__ __launch_bounds__(256) void dense1_mfma(
    const unsigned short* __restrict__ aggb, const unsigned short* __restrict__ hb,
    unsigned short* __restrict__ h3b,
    const float* __restrict__ W2l, const float* __restrict__ W2r,
    const float* __restrict__ b2) {
    __shared__ unsigned short Wt[64 * 144];
    int t = threadIdx.x;
    for (int idx = t; idx < 128 * 64; idx += 256) {
        int k = idx >> 6, j = idx & 63;
        float v = (k < 64) ? W2l[k * 64 + j] : W2r[(k - 64) * 64 + j];
        Wt[j * 144 + k] = f2b(v);
    }
    __syncthreads();
    int wib = t >> 6, lane = t & 63;
    int tile = blockIdx.x * 4 + wib;
    if (tile >= NTILES) return;
    int node0 = tile * 16;
    int jj = lane & 15, kg = lane >> 4;
    short8 bfrag[4][4];
#pragma unroll
    for (int nt = 0; nt < 4; ++nt)
#pragma unroll
        for (int s = 0; s < 4; ++s)
            bfrag[nt][s] = *(const short8*)&Wt[(nt * 16 + jj) * 144 + s * 32 + kg * 8];
    int arow = node0 + jj;
    const unsigned short* ap = aggb + (size_t)arow * 64 + kg * 8;
    const unsigned short* hp = hb + (size_t)arow * 64 + kg * 8;
    short8 afrag[4];
    afrag[0] = *(const short8*)ap;
    afrag[1] = *(const short8*)(ap + 32);
    afrag[2] = *(const short8*)hp;
    afrag[3] = *(const short8*)(hp + 32);
    const float lam = 1.0507009873554804934193349852946f;
    const float alp = 1.6732632423543772848170429916717f;
#pragma unroll
    for (int nt = 0; nt < 4; ++nt) {
        floatx4 acc = {0.f, 0.f, 0.f, 0.f};
#pragma unroll
        for (int s = 0; s < 4; ++s)
            acc = __builtin_amdgcn_mfma_f32_16x16x32_bf16(afrag[s], bfrag[nt][s], acc, 0, 0, 0);
        float bias = b2[nt * 16 + jj];
#pragma unroll
        for (int r = 0; r < 4; ++r) {
            float v = acc[r] + bias;
            float o = (v > 0.0f) ? lam * v : lam * alp * expm1f(v);
            int node = node0 + kg * 4 + r;
            h3b[(size_t)node * 64 + nt * 16 + jj] = f2b(o);
        }
    }
}

// ---------------- dense2 (MFMA) + softmax(16) ----------------
__global__ __launch_bounds__(256) void dense2_mfma(
    const unsigned short* __restrict__ aggb, const unsigned short* __restrict__ hb,
    float* __restrict__ out,
    const float* __restrict__ W3l, const float* __restrict__ W3r,
    const float* __restrict__ b3) {
    __shared__ unsigned short Wt[16 * 144];
    int t = threadIdx.x;
    for (int idx = t; idx < 128 * 16; idx += 256) {
        int k = idx >> 4, j = idx & 15;
        float v = (k < 64) ? W3l[k * 16 + j] : W3r[(k - 64) * 16 + j];
        Wt[j * 144 + k] = f2b(v);
    }
    __syncthreads();
    int wib = t >> 6, lane = t & 63;
    int tile = blockIdx.x * 4 + wib;
    if (tile >= NTILES) return;
    int node0 = tile * 16;
    int jj = lane & 15, kg = lane >> 4;
    short8 bfrag[4];
#pragma unroll
    for (int s = 0; s < 4; ++s)
        bfrag[s] = *(const short8*)&Wt[jj * 144 + s * 32 + kg * 8];
    int arow = node0 + jj;
    const unsigned short* ap = aggb + (size_t)arow * 64 + kg * 8;
    const unsigned short* hp = hb + (size_t)arow * 64 + kg * 8;
    short8 afrag[4];
    afrag[0] = *(const short8*)ap;
    afrag[1] = *(const short8*)(ap + 32);
    afrag[2] = *(const short8*)hp;
    afrag[3] = *(const short8*)(hp + 32);
    floatx4 acc = {0.f, 0.f, 0.f, 0.f};
#pragma unroll
    for (int s = 0; s < 4; ++s)
        acc = __builtin_amdgcn_mfma_f32_16x16x32_bf16(afrag[s], bfrag[s], acc, 0, 0, 0);
    float bias = b3[jj];
#pragma unroll
    for (int r = 0; r < 4; ++r) {
        float v = acc[r] + bias;
        float m = v;
        m = fmaxf(m, __shfl_xor(m, 1));
        m = fmaxf(m, __shfl_xor(m, 2));
        m = fmaxf(m, __shfl_xor(m, 4));
        m = fmaxf(m, __shfl_xor(m, 8));
        float ex = expf(v - m);
        float s2 = ex;
        s2 += __shfl_xor(s2, 1);
        s2 += __shfl_xor(s2, 2);
        s2 += __shfl_xor(s2, 4);
        s2 += __shfl_xor(s2, 8);
        int node = node0 + kg * 4 + r;
        out[(size_t)node * 16 + jj] = ex / s2;
    }
}

extern "C" void kernel_launch(void* const* d_in, const int* in_sizes, int n_in,
                              void* d_out, int out_size, void* d_ws, size_t ws_size,
                              hipStream_t stream) {
    const float* x   = (const float*)d_in[0];
    const int*   ei  = (const int*)d_in[1];
    const float* W2l = (const float*)d_in[2];
    const float* W2r = (const float*)d_in[3];
    const float* b2  = (const float*)d_in[4];
    const float* W3l = (const float*)d_in[5];
    const float* W3r = (const float*)d_in[6];
    const float* b3  = (const float*)d_in[7];
    float* out = (float*)d_out;

    const int* dst = ei;           // edge_index[0]
    const int* src = ei + NEDGES;  // edge_index[1]

    char* ws = (char*)d_ws;
    unsigned short* B0 = (unsigned short*)ws; ws += (size_t)NNODES * 64 * 2;  // g0b -> h2b
    unsigned short* B1 = (unsigned short*)ws; ws += (size_t)NNODES * 64 * 2;  // cpairs -> h1b -> h3b
    unsigned short* B2 = (unsigned short*)ws; ws += (size_t)NNODES * 64 * 2;  // fpairs -> agg1b -> agg2b
    int*      col     = (int*)ws;      ws += (size_t)NEDGES * 4;
    int*      deg     = (int*)ws;      ws += (size_t)NNODES * 4;
    int*      rowoff  = (int*)ws;      ws += (size_t)NNODES * 4;
    float*    dinv    = (float*)ws;    ws += (size_t)NNODES * 4;
    int*      gcur1   = (int*)ws;      ws += NC * 4;
    int*      gcur2   = (int*)ws;      ws += NBUCK * 4;

    // overlays (dead before their hosts are written):
    unsigned* cpairs = (unsigned*)B1;  // 25*68000*4 = 6.8 MB < 12.8 MB; dead after split2
    unsigned* fpairs = (unsigned*)B2;  // 391*4800*4 = 7.5 MB < 12.8 MB; dead after finalize
    unsigned short* h1b = B1;          // cpairs dead when written (after finalize)
    unsigned short* h2b = B0;          // g0b dead when written (after gatherw<0>)
    unsigned short* h3b = B1;          // h1b dead when written (after gatherw<1> consumed it)

    hipMemsetAsync(gcur1, 0, (NC + NBUCK) * 4, stream);  // gcur1 + gcur2 adjacent

    split1_kernel<<<NSPLIT, 256, 0, stream>>>(dst, src, gcur1, cpairs);
    split2_kernel<<<NC * T2TILES, 256, 0, stream>>>(cpairs, gcur1, gcur2, fpairs);
    finalize_kernel<<<NBUCK, 256, 0, stream>>>(fpairs, gcur2, x,
                                               col, deg, rowoff, dinv, B0);

    int nblk = NNODES / 4;                 // 25000, exact
    int ndense = (NTILES + 3) / 4;         // 1563
    // KProp step 1: h1b = bf16(x + dinv_i*sum(g0b[c]))
    gatherw_kernel<0><<<nblk, 256, 0, stream>>>(B0, x, nullptr, h1b, rowoff, deg, col, dinv);
    // KProp step 2: h2b = bf16(h1b + dinv_i*sum(dinv_c*h1b[c]))
    gatherw_kernel<1><<<nblk, 256, 0, stream>>>(h1b, nullptr, h1b, h2b, rowoff, deg, col, dinv);
    // SAGE1 aggregate: agg1b = bf16(mean(h2b[neigh]))
    gatherw_kernel<2><<<nblk, 256, 0, stream>>>(h2b, nullptr, nullptr, B2, rowoff, deg, col, dinv);
    // dense1: h3b = bf16(selu(agg1@W2l + h2@W2r + b2))
    dense1_mfma<<<ndense, 256, 0, stream>>>(B2, h2b, h3b, W2l, W2r, b2);
    // SAGE2 aggregate: agg2b = bf16(mean(h3b[neigh]))
    gatherw_kernel<2><<<nblk, 256, 0, stream>>>(h3b, nullptr, nullptr, B2, rowoff, deg, col, dinv);
    // dense2 + softmax
    dense2_mfma<<<ndense, 256, 0, stream>>>(B2, h3b, out, W3l, W3r, b3);
}

// Round 9
// 324.246 us; speedup vs baseline: 1.1824x; 1.0015x over previous
//
#include <hip/hip_runtime.h>
#include <hip/hip_bf16.h>

#define NNODES 100000
#define NEDGES 1600000
#define NBUCK 391           // fine buckets of 256 nodes (dst>>8)
#define BCAP 4800           // slack capacity per bucket (mean 4092, +11 sigma)
#define SPLIT_TILE 4096
#define NSPLIT ((NEDGES + SPLIT_TILE - 1) / SPLIT_TILE)  // 391
#define NTILES (NNODES / 16) // 6250 dense tiles, exact

typedef short short8 __attribute__((ext_vector_type(8)));
typedef unsigned short ushx8 __attribute__((ext_vector_type(8)));
typedef float floatx4 __attribute__((ext_vector_type(4)));

// f32 -> bf16 RNE
__device__ __forceinline__ unsigned short f2b(float f) {
    unsigned u = __float_as_uint(f);
    u += 0x7fffu + ((u >> 16) & 1u);
    return (unsigned short)(u >> 16);
}

__device__ __forceinline__ void acc8(float* a, ushx8 u) {
#pragma unroll
    for (int i = 0; i < 8; ++i)
        a[i] += __uint_as_float((unsigned)u[i] << 16);
}

__device__ __forceinline__ void acc8s(float* a, ushx8 u, float s) {
#pragma unroll
    for (int i = 0; i < 8; ++i)
        a[i] = fmaf(s, __uint_as_float((unsigned)u[i] << 16), a[i]);
}

// ---------------- single-pass split: 391 fine buckets by dst>>8 ----------------
// packed u32 = (src << 8) | (dst & 255)   (src < 2^17)
// No LDS edge stash: dst is re-read on the scatter pass (L2-hot).
// 391 LDS histogram addresses -> ~10-way same-address contention (vs 25/16 before).
__global__ __launch_bounds__(256) void split_kernel(
    const int* __restrict__ dst, const int* __restrict__ src,
    int* __restrict__ gcur, unsigned* __restrict__ fpairs) {
    __shared__ int lhist[NBUCK];
    __shared__ int lstart[NBUCK];
    int t = threadIdx.x;
    for (int i = t; i < NBUCK; i += 256) lhist[i] = 0;
    __syncthreads();
    int base = blockIdx.x * SPLIT_TILE;
    int n = min(SPLIT_TILE, NEDGES - base);
    for (int i = t; i < n; i += 256) {
        atomicAdd(&lhist[dst[base + i] >> 8], 1);
    }
    __syncthreads();
    for (int i = t; i < NBUCK; i += 256) {
        int c = lhist[i];
        lstart[i] = (c > 0) ? atomicAdd(&gcur[i], c) : 0;
        lhist[i] = 0;  // reuse as local cursor
    }
    __syncthreads();
    for (int i = t; i < n; i += 256) {
        int d = dst[base + i];        // L2 hit (just read above)
        int s = src[base + i];
        int k = d >> 8;
        int pos = lstart[k] + atomicAdd(&lhist[k], 1);
        fpairs[(size_t)k * BCAP + pos] = ((unsigned)s << 8) | (unsigned)(d & 255);
    }
}

// ---------------- finalize: inline bucket scan + per-bucket CSR + dinv + g0b ----------------
__global__ __launch_bounds__(256) void finalize_kernel(
    const unsigned* __restrict__ fpairs, const int* __restrict__ gcur2,
    const float* __restrict__ x,
    int* __restrict__ col, int* __restrict__ deg, int* __restrict__ rowoff,
    float* __restrict__ dinv, unsigned short* __restrict__ g0b) {
    __shared__ int ldeg[256];
    __shared__ int lcur[256];
    __shared__ float ldi[256];
    __shared__ int lsc[256];
    __shared__ int bb[NBUCK + 1];
    int k = blockIdx.x;
    int t = threadIdx.x;
    // inline exclusive scan of all 391 bucket counts (redundant per block, ~1us)
    int a2 = (2 * t < NBUCK) ? gcur2[2 * t] : 0;
    int b2v = (2 * t + 1 < NBUCK) ? gcur2[2 * t + 1] : 0;
    int ts = a2 + b2v;
    lsc[t] = ts;
    __syncthreads();
    for (int s = 1; s < 256; s <<= 1) {
        int v = (t >= s) ? lsc[t - s] : 0;
        __syncthreads();
        lsc[t] += v;
        __syncthreads();
    }
    int excl2 = lsc[t] - ts;
    if (2 * t < NBUCK) bb[2 * t] = excl2;
    if (2 * t + 1 < NBUCK) bb[2 * t + 1] = excl2 + a2;
    ldeg[t] = 0;
    __syncthreads();
    int node0 = k << 8;
    int ncount = min(256, NNODES - node0);
    int base = bb[k];
    int count = gcur2[k];
    const unsigned* pb = fpairs + (size_t)k * BCAP;
    for (int i = t; i < count; i += 256) {
        atomicAdd(&ldeg[pb[i] & 255], 1);
    }
    __syncthreads();
    int a = ldeg[t];
    lsc[t] = a;
    __syncthreads();
    for (int s = 1; s < 256; s <<= 1) {
        int v = (t >= s) ? lsc[t - s] : 0;
        __syncthreads();
        lsc[t] += v;
        __syncthreads();
    }
    int excl = lsc[t] - a;
    lcur[t] = base + excl;
    if (t < ncount) {
        int n0 = node0 + t;
        rowoff[n0] = base + excl;
        deg[n0] = a;
        float di = (a > 0) ? rsqrtf((float)a) : 0.0f;
        ldi[t] = di;
        dinv[n0] = di;
    }
    __syncthreads();
    for (int i = t; i < count; i += 256) {
        unsigned p = pb[i];
        int dl = (int)(p & 255u);
        int s = (int)(p >> 8);
        int pos = atomicAdd(&lcur[dl], 1);
        col[pos] = s;
    }
    // fused g0b = bf16(dinv * x)
    const float4* x4 = (const float4*)x;
    int f4count = ncount * 16;
    int b4 = node0 * 16;
    for (int j = t; j < f4count; j += 256) {
        float di = ldi[j >> 4];
        float4 v = x4[b4 + j];
        ushort4 u;
        u.x = f2b(di * v.x); u.y = f2b(di * v.y);
        u.z = f2b(di * v.z); u.w = f2b(di * v.w);
        *(ushort4*)(g0b + (size_t)(b4 + j) * 4) = u;
    }
}

// ---------------- kprop/agg gather: one node per wave, 8 groups x 8 lanes x 16B ----------------
// MODE 0: h1b = bf16(x + dinv_i*sum(g0b))            (residual = f32 x; vin pre-scaled)
// MODE 1: h2b = bf16(h1b + dinv_i*sum(dinv_c*h1b))   (per-edge dinv; residual = bf16 h1b)
// MODE 2: aggb = bf16(sum/degm)
template <int MODE>
__global__ __launch_bounds__(256) void gatherw_kernel(
    const unsigned short* __restrict__ vin, const float* __restrict__ hinf,
    const unsigned short* __restrict__ hinb,
    unsigned short* __restrict__ out0,
    const int* __restrict__ rowoff, const int* __restrict__ deg,
    const int* __restrict__ col, const float* __restrict__ dinv) {
    int node = blockIdx.x * 4 + (threadIdx.x >> 6);  // 25000*4 == 100000 exactly
    int lane = threadIdx.x & 63;
    int sub = lane & 7;
    int g = lane >> 3;
    int beg = rowoff[node];
    int dg = deg[node];
    int end = beg + dg;
    float af[8] = {0.f, 0.f, 0.f, 0.f, 0.f, 0.f, 0.f, 0.f};
    float bf[8] = {0.f, 0.f, 0.f, 0.f, 0.f, 0.f, 0.f, 0.f};
    int e = beg + g;
    for (; e + 8 < end; e += 16) {
        int c0 = col[e];
        int c1 = col[e + 8];
        ushx8 u0 = *(const ushx8*)(vin + (size_t)c0 * 64 + sub * 8);
        ushx8 u1 = *(const ushx8*)(vin + (size_t)c1 * 64 + sub * 8);
        if (MODE == 1) {
            float d0 = dinv[c0];
            float d1 = dinv[c1];
            acc8s(af, u0, d0);
            acc8s(bf, u1, d1);
        } else {
            acc8(af, u0);
            acc8(bf, u1);
        }
    }
    if (e < end) {
        int c0 = col[e];
        ushx8 u0 = *(const ushx8*)(vin + (size_t)c0 * 64 + sub * 8);
        if (MODE == 1) {
            float d0 = dinv[c0];
            acc8s(af, u0, d0);
        } else {
            acc8(af, u0);
        }
    }
#pragma unroll
    for (int i = 0; i < 8; ++i) {
        float v = af[i] + bf[i];
        v += __shfl_xor(v, 8);
        v += __shfl_xor(v, 16);
        v += __shfl_xor(v, 32);
        af[i] = v;
    }
    if (lane < 8) {
        size_t off = (size_t)node * 64 + lane * 8;
        ushx8 uh;
        if (MODE <= 1) {
            float di = dinv[node];
            float hv[8];
            if (MODE == 0) {
                float4 h0 = *(const float4*)(hinf + off);
                float4 h1 = *(const float4*)(hinf + off + 4);
                hv[0] = h0.x; hv[1] = h0.y; hv[2] = h0.z; hv[3] = h0.w;
                hv[4] = h1.x; hv[5] = h1.y; hv[6] = h1.z; hv[7] = h1.w;
            } else {
                ushx8 u = *(const ushx8*)(hinb + off);
#pragma unroll
                for (int i = 0; i < 8; ++i) hv[i] = __uint_as_float((unsigned)u[i] << 16);
            }
#pragma unroll
            for (int i = 0; i < 8; ++i) uh[i] = f2b(hv[i] + di * af[i]);
        } else {
            float r = 1.0f / (float)(dg > 0 ? dg : 1);
#pragma unroll
            for (int i = 0; i < 8; ++i) uh[i] = f2b(af[i] * r);
        }
        *(ushx8*)(out0 + off) = uh;
    }
}

// ---------------- dense1 (MFMA): h3 = selu([agg|h2] @ [W2l;W2r] + b2), bf16 out ----------------
__global__ __launch_bounds__(256) void dense1_mfma(
    const unsigned short* __restrict__ aggb, const unsigned short* __restrict__ hb,
    unsigned short* __restrict__ h3b,
    const float* __restrict__ W2l, const float* __restrict__ W2r,
    const float* __restrict__ b2) {
    __shared__ unsigned short Wt[64 * 144];
    int t = threadIdx.x;
    for (int idx = t; idx < 128 * 64; idx += 256) {
        int k = idx >> 6, j = idx & 63;
        float v = (k < 64) ? W2l[k * 64 + j] : W2r[(k - 64) * 64 + j];
        Wt[j * 144 + k] = f2b(v);
    }
    __syncthreads();
    int wib = t >> 6, lane = t & 63;
    int tile = blockIdx.x * 4 + wib;
    if (tile >= NTILES) return;
    int node0 = tile * 16;
    int jj = lane & 15, kg = lane >> 4;
    short8 bfrag[4][4];
#pragma unroll
    for (int nt = 0; nt < 4; ++nt)
#pragma unroll
        for (int s = 0; s < 4; ++s)
            bfrag[nt][s] = *(const short8*)&Wt[(nt * 16 + jj) * 144 + s * 32 + kg * 8];
    int arow = node0 + jj;
    const unsigned short* ap = aggb + (size_t)arow * 64 + kg * 8;
    const unsigned short* hp = hb + (size_t)arow * 64 + kg * 8;
    short8 afrag[4];
    afrag[0] = *(const short8*)ap;
    afrag[1] = *(const short8*)(ap + 32);
    afrag[2] = *(const short8*)hp;
    afrag[3] = *(const short8*)(hp + 32);
    const float lam = 1.0507009873554804934193349852946f;
    const float alp = 1.6732632423543772848170429916717f;
#pragma unroll
    for (int nt = 0; nt < 4; ++nt) {
        floatx4 acc = {0.f, 0.f, 0.f, 0.f};
#pragma unroll
        for (int s = 0; s < 4; ++s)
            acc = __builtin_amdgcn_mfma_f32_16x16x32_bf16(afrag[s], bfrag[nt][s], acc, 0, 0, 0);
        float bias = b2[nt * 16 + jj];
#pragma unroll
        for (int r = 0; r < 4; ++r) {
            float v = acc[r] + bias;
            float o = (v > 0.0f) ? lam * v : lam * alp * expm1f(v);
            int node = node0 + kg * 4 + r;
            h3b[(size_t)node * 64 + nt * 16 + jj] = f2b(o);
        }
    }
}

// ---------------- dense2 (MFMA) + softmax(16) ----------------
__global__ __launch_bounds__(256) void dense2_mfma(
    const unsigned short* __restrict__ aggb, const unsigned short* __restrict__ hb,
    float* __restrict__ out,
    const float* __restrict__ W3l, const float* __restrict__ W3r,
    const float* __restrict__ b3) {
    __shared__ unsigned short Wt[16 * 144];
    int t = threadIdx.x;
    for (int idx = t; idx < 128 * 16; idx += 256) {
        int k = idx >> 4, j = idx & 15;
        float v = (k < 64) ? W3l[k * 16 + j] : W3r[(k - 64) * 16 + j];
        Wt[j * 144 + k] = f2b(v);
    }
    __syncthreads();
    int wib = t >> 6, lane = t & 63;
    int tile = blockIdx.x * 4 + wib;
    if (tile >= NTILES) return;
    int node0 = tile * 16;
    int jj = lane & 15, kg = lane >> 4;
    short8 bfrag[4];
#pragma unroll
    for (int s = 0; s < 4; ++s)
        bfrag[s] = *(const short8*)&Wt[jj * 144 + s * 32 + kg * 8];
    int arow = node0 + jj;
    const unsigned short* ap = aggb + (size_t)arow * 64 + kg * 8;
    const unsigned short* hp = hb + (size_t)arow * 64 + kg * 8;
    short8 afrag[4];
    afrag[0] = *(const short8*)ap;
    afrag[1] = *(const short8*)(ap + 32);
    afrag[2] = *(const short8*)hp;
    afrag[3] = *(const short8*)(hp + 32);
    floatx4 acc = {0.f, 0.f, 0.f, 0.f};
#pragma unroll
    for (int s = 0; s < 4; ++s)
        acc = __builtin_amdgcn_mfma_f32_16x16x32_bf16(afrag[s], bfrag[s], acc, 0, 0, 0);
    float bias = b3[jj];
#pragma unroll
    for (int r = 0; r < 4; ++r) {
        float v = acc[r] + bias;
        float m = v;
        m = fmaxf(m, __shfl_xor(m, 1));
        m = fmaxf(m, __shfl_xor(m, 2));
        m = fmaxf(m, __shfl_xor(m, 4));
        m = fmaxf(m, __shfl_xor(m, 8));
        float ex = expf(v - m);
        float s2 = ex;
        s2 += __shfl_xor(s2, 1);
        s2 += __shfl_xor(s2, 2);
        s2 += __shfl_xor(s2, 4);
        s2 += __shfl_xor(s2, 8);
        int node = node0 + kg * 4 + r;
        out[(size_t)node * 16 + jj] = ex / s2;
    }
}

extern "C" void kernel_launch(void* const* d_in, const int* in_sizes, int n_in,
                              void* d_out, int out_size, void* d_ws, size_t ws_size,
                              hipStream_t stream) {
    const float* x   = (const float*)d_in[0];
    const int*   ei  = (const int*)d_in[1];
    const float* W2l = (const float*)d_in[2];
    const float* W2r = (const float*)d_in[3];
    const float* b2  = (const float*)d_in[4];
    const float* W3l = (const float*)d_in[5];
    const float* W3r = (const float*)d_in[6];
    const float* b3  = (const float*)d_in[7];
    float* out = (float*)d_out;

    const int* dst = ei;           // edge_index[0]
    const int* src = ei + NEDGES;  // edge_index[1]

    char* ws = (char*)d_ws;
    unsigned short* B0 = (unsigned short*)ws; ws += (size_t)NNODES * 64 * 2;  // g0b -> h2b
    unsigned short* B1 = (unsigned short*)ws; ws += (size_t)NNODES * 64 * 2;  // h1b -> h3b
    unsigned short* B2 = (unsigned short*)ws; ws += (size_t)NNODES * 64 * 2;  // agg1b -> agg2b
    unsigned* fpairs  = (unsigned*)ws; ws += (size_t)NBUCK * BCAP * 4;        // 7.5 MB
    int*      col     = (int*)ws;      ws += (size_t)NEDGES * 4;
    int*      deg     = (int*)ws;      ws += (size_t)NNODES * 4;
    int*      rowoff  = (int*)ws;      ws += (size_t)NNODES * 4;
    float*    dinv    = (float*)ws;    ws += (size_t)NNODES * 4;
    int*      gcur    = (int*)ws;      ws += NBUCK * 4;

    unsigned short* h1b = B1;
    unsigned short* h2b = B0;          // g0b dead after gatherw<0>
    unsigned short* h3b = B1;          // h1b dead after gatherw<1> consumed it

    hipMemsetAsync(gcur, 0, NBUCK * 4, stream);

    split_kernel<<<NSPLIT, 256, 0, stream>>>(dst, src, gcur, fpairs);
    finalize_kernel<<<NBUCK, 256, 0, stream>>>(fpairs, gcur, x,
                                               col, deg, rowoff, dinv, B0);

    int nblk = NNODES / 4;                 // 25000, exact
    int ndense = (NTILES + 3) / 4;         // 1563
    // KProp step 1: h1b = bf16(x + dinv_i*sum(g0b[c]))
    gatherw_kernel<0><<<nblk, 256, 0, stream>>>(B0, x, nullptr, h1b, rowoff, deg, col, dinv);
    // KProp step 2: h2b = bf16(h1b + dinv_i*sum(dinv_c*h1b[c]))
    gatherw_kernel<1><<<nblk, 256, 0, stream>>>(h1b, nullptr, h1b, h2b, rowoff, deg, col, dinv);
    // SAGE1 aggregate: agg1b = bf16(mean(h2b[neigh]))
    gatherw_kernel<2><<<nblk, 256, 0, stream>>>(h2b, nullptr, nullptr, B2, rowoff, deg, col, dinv);
    // dense1: h3b = bf16(selu(agg1@W2l + h2@W2r + b2))
    dense1_mfma<<<ndense, 256, 0, stream>>>(B2, h2b, h3b, W2l, W2r, b2);
    // SAGE2 aggregate: agg2b = bf16(mean(h3b[neigh]))
    gatherw_kernel<2><<<nblk, 256, 0, stream>>>(h3b, nullptr, nullptr, B2, rowoff, deg, col, dinv);
    // dense2 + softmax
    dense2_mfma<<<ndense, 256, 0, stream>>>(B2, h3b, out, W3l, W3r, b3);
}